// Round 5
// baseline (3597.816 us; speedup 1.0000x reference)
//
#include <hip/hip_runtime.h>

typedef unsigned short u16;
typedef __bf16 bf16x8 __attribute__((ext_vector_type(8)));
typedef float floatx4 __attribute__((ext_vector_type(4)));

#define C_  256
#define NTOK 131072                  // B*D*H*W = 8*4*64*64
#define QSCALE 0.17677669529663687f  // 1/sqrt(32)

// ws: 128 MiB as two bf16 regions of NTOK*256 elems.
// r0: xw -> q (in-place) -> o (in-place) -> oproj (in-place) -> h1 -> h2
// r1: xn
// d_out (134 MB fp32): [k | v] as bf16 halves during attention, then y/out fp32.
#define R1_ELEMS 33554432ull

__device__ __forceinline__ float bf2f(u16 u) {
    return __uint_as_float(((unsigned)u) << 16);
}
__device__ __forceinline__ u16 f2bf(float f) {
    unsigned u = __float_as_uint(f);
    return (u16)((u + 0x7FFFu + ((u >> 16) & 1u)) >> 16);  // RNE
}

// ---------------------------------------------------------- LN1 + partition
// x fp32 -> xw bf16 (window layout)
__global__ __launch_bounds__(256) void ln_part_kernel(
    const float* __restrict__ x, const float* __restrict__ g, const float* __restrict__ bb,
    u16* __restrict__ xw)
{
    const int lane = threadIdx.x & 63;
    const int wave = threadIdx.x >> 6;
    const int t = blockIdx.x * 4 + wave;          // window row: wb*256+n
    const int wb = t >> 8, n = t & 255;
    const int bidx = wb >> 6, hb = (wb >> 3) & 7, wbl = wb & 7;
    const int d = n >> 6, hh = (n >> 3) & 7, ww = n & 7;
    const size_t src = ((((size_t)bidx * 4 + d) * 64 + hb * 8 + hh) * 64 + wbl * 8 + ww) * C_;
    const int c0 = lane * 4;
    float4 raw = *reinterpret_cast<const float4*>(&x[src + c0]);
    float v0 = raw.x, v1 = raw.y, v2 = raw.z, v3 = raw.w;
    float s = v0 + v1 + v2 + v3;
    float sq = v0 * v0 + v1 * v1 + v2 * v2 + v3 * v3;
#pragma unroll
    for (int off = 32; off > 0; off >>= 1) {
        s  += __shfl_xor(s, off, 64);
        sq += __shfl_xor(sq, off, 64);
    }
    const float mean = s * (1.0f / 256.0f);
    const float var  = sq * (1.0f / 256.0f) - mean * mean;
    const float rstd = rsqrtf(var + 1e-5f);
    float4 gr = *reinterpret_cast<const float4*>(&g[c0]);
    float4 br = *reinterpret_cast<const float4*>(&bb[c0]);
    ushort4 outv;
    outv.x = f2bf((v0 - mean) * rstd * gr.x + br.x);
    outv.y = f2bf((v1 - mean) * rstd * gr.y + br.y);
    outv.z = f2bf((v2 - mean) * rstd * gr.z + br.z);
    outv.w = f2bf((v3 - mean) * rstd * gr.w + br.w);
    *reinterpret_cast<ushort4*>(&xw[(size_t)t * C_ + c0]) = outv;
}

// ------------------------------------------------- residual + LN2
// x fp32 + oproj bf16 (window layout) -> y fp32 (d_out, x layout), xn bf16 (x layout)
__global__ __launch_bounds__(256) void resid_ln2_kernel(
    const float* __restrict__ x, const u16* __restrict__ oproj,
    const float* __restrict__ g, const float* __restrict__ bb,
    float* __restrict__ y, u16* __restrict__ xn)
{
    const int lane = threadIdx.x & 63;
    const int wave = threadIdx.x >> 6;
    const int t = blockIdx.x * 4 + wave;          // x-layout token
    const int wpos = t & 63;
    const int h = (t >> 6) & 63;
    const int d = (t >> 12) & 3;
    const int bidx = t >> 14;
    const int wr = (((bidx * 8) + (h >> 3)) * 8 + (wpos >> 3)) * 256
                 + d * 64 + (h & 7) * 8 + (wpos & 7);   // window row
    const int c0 = lane * 4;
    float4 xr = *reinterpret_cast<const float4*>(&x[(size_t)t * C_ + c0]);
    ushort4 pr = *reinterpret_cast<const ushort4*>(&oproj[(size_t)wr * C_ + c0]);
    float v0 = xr.x + bf2f(pr.x);
    float v1 = xr.y + bf2f(pr.y);
    float v2 = xr.z + bf2f(pr.z);
    float v3 = xr.w + bf2f(pr.w);
    float s = v0 + v1 + v2 + v3;
    float sq = v0 * v0 + v1 * v1 + v2 * v2 + v3 * v3;
#pragma unroll
    for (int off = 32; off > 0; off >>= 1) {
        s  += __shfl_xor(s, off, 64);
        sq += __shfl_xor(sq, off, 64);
    }
    const float mean = s * (1.0f / 256.0f);
    const float var  = sq * (1.0f / 256.0f) - mean * mean;
    const float rstd = rsqrtf(var + 1e-5f);
    float4 yv; yv.x = v0; yv.y = v1; yv.z = v2; yv.w = v3;
    *reinterpret_cast<float4*>(&y[(size_t)t * C_ + c0]) = yv;
    float4 gr = *reinterpret_cast<const float4*>(&g[c0]);
    float4 br = *reinterpret_cast<const float4*>(&bb[c0]);
    ushort4 nv;
    nv.x = f2bf((v0 - mean) * rstd * gr.x + br.x);
    nv.y = f2bf((v1 - mean) * rstd * gr.y + br.y);
    nv.z = f2bf((v2 - mean) * rstd * gr.z + br.z);
    nv.w = f2bf((v3 - mean) * rstd * gr.w + br.w);
    *reinterpret_cast<ushort4*>(&xn[(size_t)t * C_ + c0]) = nv;
}

// ----------------------------------------------------------- MFMA bf16 GEMM
// Fixed shape: M=NTOK, N=256, K=256. One block per 128-row strip (full N).
// A: bf16 [M x 256]. Bgf: fp32 natural [256 x ldb], column window [nc0,nc0+256),
// converted to bf16 during in-LDS transpose. bias fp32.
// mode: 0 plain->Cm(bf16), 1 +bias->Cm, 2 +bias+GELU->Cm,
//       5 Cf(fp32) = Cf + acc + bias, 6 Cf = Cf + acc.
// In-place safe (Cm aliasing A region): blocks read only their own 128-row
// strip (all reads before final barrier) and write only that strip.
__global__ __launch_bounds__(256) void gemm256_kernel(
    const u16* __restrict__ A, const float* __restrict__ Bgf, int ldb, int nc0,
    u16* __restrict__ Cm, float* __restrict__ Cf, const float* __restrict__ bias,
    int mode)
{
    __shared__ __align__(16) u16 As[128][40];   // [row][k], padded
    __shared__ __align__(16) u16 Bs[256][40];   // [n][k],  padded (B^T tile)
    const int tid  = threadIdx.x;
    const int lane = tid & 63, wave = tid >> 6;
    const int lr = lane & 15, lq = lane >> 4;
    const int row0 = blockIdx.x * 128;
    const int wm = (wave & 1) * 64;      // m offset within tile
    const int wn = (wave >> 1) * 128;    // n offset within tile

    floatx4 acc[4][8] = {};

    for (int k0 = 0; k0 < 256; k0 += 32) {
        // stage A: 128 rows x 32 k, vectorized bf16
#pragma unroll
        for (int t = 0; t < 2; ++t) {
            int c = tid + t * 256;            // 0..511
            int r = c >> 2, cc = c & 3;
            *reinterpret_cast<float4*>(&As[r][cc * 8]) =
                *reinterpret_cast<const float4*>(&A[(size_t)(row0 + r) * 256 + k0 + cc * 8]);
        }
        // stage B (fp32 -> bf16) with in-LDS transpose: 32 k-rows x 256 n
#pragma unroll
        for (int t = 0; t < 8; ++t) {
            int c = tid + t * 256;            // 0..2047
            int kk = c >> 6, ng = c & 63;     // k-row, n-group of 4
            float4 bv = *reinterpret_cast<const float4*>(
                &Bgf[(size_t)(k0 + kk) * ldb + nc0 + ng * 4]);
            Bs[ng * 4 + 0][kk] = f2bf(bv.x);
            Bs[ng * 4 + 1][kk] = f2bf(bv.y);
            Bs[ng * 4 + 2][kk] = f2bf(bv.z);
            Bs[ng * 4 + 3][kk] = f2bf(bv.w);
        }
        __syncthreads();
        bf16x8 af[4], bfv[8];
#pragma unroll
        for (int mt = 0; mt < 4; ++mt)
            af[mt] = *reinterpret_cast<const bf16x8*>(&As[wm + mt * 16 + lr][lq * 8]);
#pragma unroll
        for (int nt = 0; nt < 8; ++nt)
            bfv[nt] = *reinterpret_cast<const bf16x8*>(&Bs[wn + nt * 16 + lr][lq * 8]);
#pragma unroll
        for (int mt = 0; mt < 4; ++mt)
#pragma unroll
            for (int nt = 0; nt < 8; ++nt)
                acc[mt][nt] = __builtin_amdgcn_mfma_f32_16x16x32_bf16(
                    af[mt], bfv[nt], acc[mt][nt], 0, 0, 0);
        __syncthreads();
    }

#pragma unroll
    for (int mt = 0; mt < 4; ++mt) {
#pragma unroll
        for (int nt = 0; nt < 8; ++nt) {
#pragma unroll
            for (int r = 0; r < 4; ++r) {
                int row = row0 + wm + mt * 16 + lq * 4 + r;
                int col = wn + nt * 16 + lr;
                size_t idx = (size_t)row * 256 + col;
                float v = acc[mt][nt][r];
                if (mode == 1 || mode == 2 || mode == 5) v += bias[col];
                if (mode == 2) v = 0.5f * v * (1.0f + erff(v * 0.70710678118654752f));
                if (mode >= 5) {
                    v += Cf[idx];          // fp32 accumulate in place (own element)
                    Cf[idx] = v;
                } else {
                    Cm[idx] = f2bf(v);
                }
            }
        }
    }
}

// -------------------------------------------------------------- attention
// block = (window wb, depth-slice i); 8 heads sequential. 64 q x 192 keys.
// qo: q buffer (bf16), overwritten in place with o. rpb fp32.
// LDS: 5120 + 15360 + 15360 + 25600 = 61440 B < 64 KB.
__global__ __launch_bounds__(256) void attn_kernel(
    u16* __restrict__ qo, const u16* __restrict__ kb, const u16* __restrict__ vb,
    const float* __restrict__ rpbp)
{
    __shared__ __align__(16) u16 qh[64][40];
    __shared__ __align__(16) u16 kt[192][40];
    __shared__ __align__(16) u16 vt[192][40];
    __shared__ u16 sc[64][200];

    const int wb = blockIdx.x >> 2;
    const int i  = blockIdx.x & 3;
    const int tid = threadIdx.x;
    const size_t qbase = ((size_t)(wb * 256 + i * 64)) * C_;

    for (int h = 0; h < 8; ++h) {
        // stage q_h: 64 rows x 32 cols
        {
            int row = tid >> 2, g = tid & 3;
            *reinterpret_cast<float4*>(&qh[row][g * 8]) =
                *reinterpret_cast<const float4*>(&qo[qbase + (size_t)row * C_ + h * 32 + g * 8]);
        }
        // stage k_h, v_h: 192 key tokens x 32 cols
#pragma unroll
        for (int t = 0; t < 3; ++t) {
            int c = tid + t * 256;
            int kl = c >> 2, g = c & 3;
            int nk = (kl < i * 64) ? kl : kl + 64;
            size_t base = ((size_t)(wb * 256 + nk)) * C_ + h * 32 + g * 8;
            *reinterpret_cast<float4*>(&kt[kl][g * 8]) =
                *reinterpret_cast<const float4*>(&kb[base]);
            *reinterpret_cast<float4*>(&vt[kl][g * 8]) =
                *reinterpret_cast<const float4*>(&vb[base]);
        }
        __syncthreads();

        // scores: register tile 4 (q) x 12 (k) per thread, fp32 accumulate
        {
            const int ti = tid & 15, tj = tid >> 4;
            float acc[4][12] = {};
            for (int c = 0; c < 32; ++c) {
                float qv[4], kv[12];
#pragma unroll
                for (int r = 0; r < 4; ++r) qv[r] = bf2f(qh[ti * 4 + r][c]);
#pragma unroll
                for (int j = 0; j < 12; ++j) kv[j] = bf2f(kt[tj * 12 + j][c]);
#pragma unroll
                for (int r = 0; r < 4; ++r)
#pragma unroll
                    for (int j = 0; j < 12; ++j) acc[r][j] += qv[r] * kv[j];
            }
#pragma unroll
            for (int r = 0; r < 4; ++r) {
                int ql = ti * 4 + r;
                int hq = ql >> 3, wq_ = ql & 7;
#pragma unroll
                for (int j = 0; j < 12; ++j) {
                    int kl = tj * 12 + j;
                    int nk = (kl < i * 64) ? kl : kl + 64;
                    int dk = nk >> 6, hk = (nk >> 3) & 7, wk = nk & 7;
                    int rel = (i - dk + 3) * 225 + (hq - hk + 7) * 15 + (wq_ - wk + 7);
                    sc[ql][kl] = f2bf(acc[r][j] * QSCALE + rpbp[rel * 8 + h]);
                }
            }
        }
        __syncthreads();

        // softmax per row (fp32 math, bf16 storage)
        if (tid < 64) {
            float m = -1e30f;
            for (int kl = 0; kl < 192; ++kl) m = fmaxf(m, bf2f(sc[tid][kl]));
            float s = 0.f;
            for (int kl = 0; kl < 192; ++kl) {
                float ev = __expf(bf2f(sc[tid][kl]) - m);
                s += ev;
                sc[tid][kl] = f2bf(ev);
            }
            float inv = 1.0f / s;
            for (int kl = 0; kl < 192; ++kl)
                sc[tid][kl] = f2bf(bf2f(sc[tid][kl]) * inv);
        }
        __syncthreads();

        // PV: register tile 4 (q) x 2 (hd) per thread; write o over q cols
        {
            const int ti = tid & 15, tjj = tid >> 4;
            float a2[4][2] = {};
            for (int kl = 0; kl < 192; ++kl) {
                float p[4], vv[2];
#pragma unroll
                for (int r = 0; r < 4; ++r) p[r] = bf2f(sc[ti * 4 + r][kl]);
#pragma unroll
                for (int j = 0; j < 2; ++j) vv[j] = bf2f(vt[kl][tjj * 2 + j]);
#pragma unroll
                for (int r = 0; r < 4; ++r)
#pragma unroll
                    for (int j = 0; j < 2; ++j) a2[r][j] += p[r] * vv[j];
            }
#pragma unroll
            for (int r = 0; r < 4; ++r) {
                size_t ob = qbase + (size_t)(ti * 4 + r) * C_ + h * 32 + tjj * 2;
#pragma unroll
                for (int j = 0; j < 2; ++j) qo[ob + j] = f2bf(a2[r][j]);
            }
        }
        __syncthreads();   // protect LDS restage next head
    }
}

// ----------------------------------------------------------------- launch
extern "C" void kernel_launch(void* const* d_in, const int* in_sizes, int n_in,
                              void* d_out, int out_size, void* d_ws, size_t ws_size,
                              hipStream_t stream) {
    const float* x    = (const float*)d_in[0];
    const float* ln1g = (const float*)d_in[1];
    const float* ln1b = (const float*)d_in[2];
    const float* ln2g = (const float*)d_in[3];
    const float* ln2b = (const float*)d_in[4];
    const float* wq   = (const float*)d_in[5];
    const float* wkv  = (const float*)d_in[6];
    const float* wp   = (const float*)d_in[7];
    const float* bp   = (const float*)d_in[8];
    const float* rpb  = (const float*)d_in[9];
    const float* w1   = (const float*)d_in[10];
    const float* b1   = (const float*)d_in[11];
    const float* w2   = (const float*)d_in[12];
    const float* b2   = (const float*)d_in[13];
    float* outf = (float*)d_out;
    u16*   outu = (u16*)d_out;          // bf16 scratch view: [k | v]
    u16*   ws16 = (u16*)d_ws;

    u16* r0 = ws16;                     // xw -> q -> o -> oproj -> h1 -> h2
    u16* r1 = ws16 + R1_ELEMS;          // xn
    u16* kbuf = outu;
    u16* vbuf = outu + R1_ELEMS;

    // 1. LN1 + window partition (fp32 -> bf16)
    ln_part_kernel<<<NTOK / 4, 256, 0, stream>>>(x, ln1g, ln1b, r0);

    // 2. k, v = xw @ wkv halves -> d_out bf16 halves
    gemm256_kernel<<<NTOK / 128, 256, 0, stream>>>(r0, wkv, 512, 0,   kbuf, nullptr, nullptr, 0);
    gemm256_kernel<<<NTOK / 128, 256, 0, stream>>>(r0, wkv, 512, 256, vbuf, nullptr, nullptr, 0);
    // 3. q = xw @ wq -> r0 (in-place)
    gemm256_kernel<<<NTOK / 128, 256, 0, stream>>>(r0, wq, 256, 0, r0, nullptr, nullptr, 0);

    // 4. attention: o overwrites q in r0
    attn_kernel<<<512 * 4, 256, 0, stream>>>(r0, kbuf, vbuf, rpb);

    // 5. oproj = o @ wp + bp -> r0 (in-place)
    gemm256_kernel<<<NTOK / 128, 256, 0, stream>>>(r0, wp, 256, 0, r0, nullptr, bp, 1);

    // 6. y = x + reverse(oproj) -> d_out fp32 (k,v dead); xn = LN2(y) -> r1
    resid_ln2_kernel<<<NTOK / 4, 256, 0, stream>>>(x, r0, ln2g, ln2b, outf, r1);

    // 7. MLP, hid split in two 256-halves, fp32 accumulation into d_out
    gemm256_kernel<<<NTOK / 128, 256, 0, stream>>>(r1, w1, 512, 0,   r0, nullptr, b1, 2);        // h1
    gemm256_kernel<<<NTOK / 128, 256, 0, stream>>>(r0, w2, 256, 0,   nullptr, outf, b2, 5);      // out = y + b2 + h1@w2a
    gemm256_kernel<<<NTOK / 128, 256, 0, stream>>>(r1, w1, 512, 256, r0, nullptr, b1 + 256, 2);  // h2
    gemm256_kernel<<<NTOK / 128, 256, 0, stream>>>(r0, w2 + 65536, 256, 0, nullptr, outf, nullptr, 6); // out += h2@w2b
}